// Round 13
// baseline (632.501 us; speedup 1.0000x reference)
//
#include <hip/hip_runtime.h>
#include <math.h>

#define NBINS 100
#define NCOPY 32    // LDS-hist copy index = tid&31 -> bank = tid&31: conflict-free (R5-proven)
#define NREP  512   // global-table replicas (d_ws), ~3 blocks/table
#define GOFF  256   // gtab starts at d_ws dword 256
static constexpr float LM1f  = -4.605170185988091f;  // log(0.01)
static constexpr float LM2f  =  5.991464547107982f;  // log(400)
static constexpr float EPSV  = 1e-5f;
static constexpr float BETA  = 0.1f;

// Workspace (uint32 units): [0]=sumsq(float), [1..100]=hp, [101..200]=ha,
// [256 .. 256+512*200) = global replica tables [rep][200] (0..99 pred, 100..199 act)
//
// HW model (R2-R10): LDS pipe = ~1 scattered lane-op/cy/CU with structured banking
// (R5: 108.7us at 1 conflict-free atomic/value = saturated); joint tables 10x worse
// (same-word cross-wave serialization); VALU counters unforceable (3x spill).
// This round: split histogram work across TWO pipes -- 8/16 values via R5's LDS
// atomics (DS pipe ~55us), 8/16 via global atomicAdd into L2-resident replicated
// tables (TCC RMW pipe, concurrent, fire-and-forget, ~300 G/s aggregate).
__global__ __launch_bounds__(256) void mse_hist_kernel(
    const float4* __restrict__ pred4, const float4* __restrict__ act4,
    const float* __restrict__ pred_s, const float* __restrict__ act_s,
    long long n,
    float* __restrict__ sumsq, unsigned int* __restrict__ hp,
    unsigned int* __restrict__ ha, unsigned int* __restrict__ gtab)
{
    __shared__ unsigned int sh[2 * NBINS * NCOPY];   // 25.6 KB -> 6 blocks/CU
    const int tid = threadIdx.x;
    for (int i = tid; i < 2 * NBINS * NCOPY; i += 256) sh[i] = 0u;
    __syncthreads();

    const int   c     = tid & (NCOPY - 1);
    const float scale = (float)NBINS / (LM2f - LM1f);
    unsigned int* __restrict__ gt = gtab + (unsigned)(blockIdx.x & (NREP - 1)) * (2 * NBINS);

    // LDS path (R5): slot s = off+bin; addr = s*32 + c -> bank = c (conflict-free)
#define BUMP(xv, off) do {                                            \
        float x_ = (xv);                                              \
        if (x_ >= LM1f && x_ <= LM2f) {                               \
            int b_ = (int)((x_ - LM1f) * scale);                      \
            if (b_ > NBINS - 1) b_ = NBINS - 1;                       \
            atomicAdd(&sh[(((off) + b_) << 5) + c], 1u);              \
        }                                                             \
    } while (0)

    // Global path: fire-and-forget atomic into this block's replica (L2-resident)
#define GBUMP(xv, off) do {                                           \
        float x_ = (xv);                                              \
        if (x_ >= LM1f && x_ <= LM2f) {                               \
            int b_ = (int)((x_ - LM1f) * scale);                      \
            if (b_ > NBINS - 1) b_ = NBINS - 1;                       \
            atomicAdd(&gt[(off) + b_], 1u);                           \
        }                                                             \
    } while (0)

    float acc = 0.f;
    const long long n8     = n >> 3;
    const long long stride = (long long)gridDim.x * 256;
    long long i = (long long)blockIdx.x * 256 + tid;

    // 2-deep register pipeline (R5-proven).
    float4 p0, p1, a0, a1;
    bool have = (i < n8);
    if (have) {
        p0 = pred4[2 * i]; p1 = pred4[2 * i + 1];
        a0 = act4[2 * i];  a1 = act4[2 * i + 1];
    }
    while (have) {
        const long long ni = i + stride;
        const bool hn = (ni < n8);
        float4 q0, q1, b0, b1;
        if (hn) {
            q0 = pred4[2 * ni]; q1 = pred4[2 * ni + 1];
            b0 = act4[2 * ni];  b1 = act4[2 * ni + 1];
        }
        float d;
        d = p0.x - a0.x; acc = fmaf(d, d, acc);
        d = p0.y - a0.y; acc = fmaf(d, d, acc);
        d = p0.z - a0.z; acc = fmaf(d, d, acc);
        d = p0.w - a0.w; acc = fmaf(d, d, acc);
        d = p1.x - a1.x; acc = fmaf(d, d, acc);
        d = p1.y - a1.y; acc = fmaf(d, d, acc);
        d = p1.z - a1.z; acc = fmaf(d, d, acc);
        d = p1.w - a1.w; acc = fmaf(d, d, acc);

        // DS pipe: 8 values
        BUMP(p0.x, 0);      BUMP(p0.y, 0);
        BUMP(p1.x, 0);      BUMP(p1.y, 0);
        BUMP(a0.x, NBINS);  BUMP(a0.y, NBINS);
        BUMP(a1.x, NBINS);  BUMP(a1.y, NBINS);

        // TCC pipe: 8 values (concurrent with DS)
        GBUMP(p0.z, 0);     GBUMP(p0.w, 0);
        GBUMP(p1.z, 0);     GBUMP(p1.w, 0);
        GBUMP(a0.z, NBINS); GBUMP(a0.w, NBINS);
        GBUMP(a1.z, NBINS); GBUMP(a1.w, NBINS);

        p0 = q0; p1 = q1; a0 = b0; a1 = b1;
        i = ni; have = hn;
    }

    // Scalar tail (n % 8 != 0) — thread 0 of block 0, LDS path.
    if (blockIdx.x == 0 && tid == 0) {
        for (long long j = 8 * n8; j < n; ++j) {
            float p = pred_s[j], a = act_s[j];
            float d = p - a; acc = fmaf(d, d, acc);
            BUMP(p, 0);
            BUMP(a, NBINS);
        }
    }
#undef GBUMP
#undef BUMP
    __syncthreads();

    // Flush LDS hist: collapse 32 copies (rotated reads, bank=(k+tid)&31) -> hp/ha.
    if (tid < 2 * NBINS) {
        unsigned int s = 0;
        #pragma unroll
        for (int k = 0; k < NCOPY; ++k)
            s += sh[(tid << 5) + ((k + tid) & 31)];
        if (s) {
            if (tid < NBINS) atomicAdd(&hp[tid], s);
            else             atomicAdd(&ha[tid - NBINS], s);
        }
    }

    // Block-reduce squared-diff (wave64 shuffle, then LDS).
    for (int off = 32; off > 0; off >>= 1)
        acc += __shfl_down(acc, off);
    __shared__ float wsum[4];
    if ((tid & 63) == 0) wsum[tid >> 6] = acc;
    __syncthreads();
    if (tid == 0)
        atomicAdd(sumsq, wsum[0] + wsum[1] + wsum[2] + wsum[3]);
}

// Kernel 2: fold 512 global replicas into bins, normalize, KLD, combine. 256 threads.
__global__ __launch_bounds__(256) void finalize_kernel(
    const float* __restrict__ sumsq, const unsigned int* __restrict__ hp,
    const unsigned int* __restrict__ ha, const unsigned int* __restrict__ gtab,
    float* __restrict__ out, float n_elems)
{
    const int t = threadIdx.x;
    __shared__ float tot[2 * NBINS];

    if (t < 2 * NBINS) {
        unsigned int s = (t < NBINS) ? hp[t] : ha[t - NBINS];
        for (int r = 0; r < NREP; ++r)            // [rep][bin]: consecutive t coalesced
            s += gtab[r * (2 * NBINS) + t];
        tot[t] = (float)s;
    }
    __syncthreads();

    float hpv = 0.f, hav = 0.f;
    if (t < NBINS) {
        hpv = tot[t] + EPSV;
        hav = tot[NBINS + t] + EPSV;
    }
    float sp = hpv, sa = hav;
    for (int off = 32; off > 0; off >>= 1) {
        sp += __shfl_down(sp, off);
        sa += __shfl_down(sa, off);
    }
    __shared__ float shp[4], sha[4];
    if ((t & 63) == 0) { shp[t >> 6] = sp; sha[t >> 6] = sa; }
    __syncthreads();
    const float tot_p = shp[0] + shp[1] + shp[2] + shp[3];
    const float tot_a = sha[0] + sha[1] + sha[2] + sha[3];

    float term = 0.f;
    if (t < NBINS) {
        float pv = hpv / tot_p;
        float av = hav / tot_a;
        term = av * (logf(av) - logf(pv));
    }
    for (int off = 32; off > 0; off >>= 1)
        term += __shfl_down(term, off);
    __shared__ float st[4];
    if ((t & 63) == 0) st[t >> 6] = term;
    __syncthreads();
    if (t == 0) {
        float kld = (st[0] + st[1] + st[2] + st[3]) / (float)NBINS;
        out[0] = sumsq[0] / n_elems + BETA * kld;
    }
}

extern "C" void kernel_launch(void* const* d_in, const int* in_sizes, int n_in,
                              void* d_out, int out_size, void* d_ws, size_t ws_size,
                              hipStream_t stream) {
    const float* pred = (const float*)d_in[0];
    const float* act  = (const float*)d_in[1];
    const long long n = (long long)in_sizes[0];

    float*        sumsq = (float*)d_ws;
    unsigned int* hp    = (unsigned int*)d_ws + 1;
    unsigned int* ha    = (unsigned int*)d_ws + 1 + NBINS;
    unsigned int* gtab  = (unsigned int*)d_ws + GOFF;

    // Zero scalar+bins+replicas: (256 + 512*200)*4 = 410,624 B (well within ws).
    hipMemsetAsync(d_ws, 0, (GOFF + NREP * 2 * NBINS) * sizeof(unsigned int), stream);

    // 1536 blocks = 6 blocks/CU (25.6 KB LDS each), R5-proven occupancy.
    mse_hist_kernel<<<1536, 256, 0, stream>>>(
        (const float4*)pred, (const float4*)act, pred, act, n, sumsq, hp, ha, gtab);

    finalize_kernel<<<1, 256, 0, stream>>>(sumsq, hp, ha, gtab, (float*)d_out, (float)n);
}